// Round 1
// 170.427 us; speedup vs baseline: 1.0017x; 1.0017x over previous
//
#include <hip/hip_runtime.h>
#include <math.h>

#define W 512
#define H 512
#define NPIX (W*H)
#define RAD 10
#define KS 21
#define CRF_EPS 1e-4f

// tile geometry: TX x TY outputs per block, halo RAD each side
#define TX 32
#define TY 8
#define CIN (TX + 2*RAD)   // 52
#define RIN (TY + 2*RAD)   // 28
#define GX (W / TX)        // 16
#define GY (H / TY)        // 64
#define NBLK (GX*GY)       // 1024 blocks
#define NVT (CIN * 4)      // 208 V-phase threads (2 output rows each)

// Cooperative-kernel LDS (29,952 B => 5 blocks/CU LDS capacity):
//  region0 [0, 23296): staging sQ/sT/s2t; post-V aliases i0 [0,6656),
//                      i1 [6656,13312), ib [0,6656); s1 V-out ii0 (3328)
//  region1 [23296, 29952): sG gray tile (5824) during f1 V / i2 after;
//                          ia in f2; ii1 in s2
#define SM_BYTES 29952
#define OFF_R1 23296

// neighbor-sync flags: one 128B-strided slot per logical tile
#define FLAG_STRIDE 32     // in u32 units => 128 B per flag

struct W21 { float w[KS]; };

struct Params {
    const float4* unary;
    const float*  image;
    float*  gray;
    float4* Q;
    float2* a1b1;
    float4* a_arr;
    float4* b_arr;
    float4* Qfinal;
    unsigned* flags;
    W21 wg, wu;
    float c0g, c0u;
};

__device__ __forceinline__ float4 f4(float x, float y, float z, float w_) {
    return make_float4(x, y, z, w_);
}
__device__ __forceinline__ float4 fma4(float s, float4 a, float4 acc) {
    acc.x = fmaf(s, a.x, acc.x); acc.y = fmaf(s, a.y, acc.y);
    acc.z = fmaf(s, a.z, acc.z); acc.w = fmaf(s, a.w, acc.w);
    return acc;
}
__device__ __forceinline__ int swz(int b, int N) {
    return (b & 7) * (N >> 3) + (b >> 3);
}

// ---- producer/consumer neighborhood sync (replaces grid.sync) ----
// All phase dependencies have radius <= RAD=10 < TX, and 10 <= 2*TY,
// so the producer set for any halo read is the 3x5 tile neighborhood
// (dx in [-1,1], dy in [-2,2]). publish() is called only after BOTH the
// block's global writes of this phase AND its staging reads of the prior
// phase's arrays are complete, which also covers all WAR hazards.

__device__ __forceinline__ void publish(unsigned* flags, int L, unsigned v) {
    __syncthreads();   // all lanes' reads+writes of this phase done
    if (threadIdx.x == 0)
        __hip_atomic_store(flags + (size_t)L * FLAG_STRIDE, v,
                           __ATOMIC_RELEASE, __HIP_MEMORY_SCOPE_AGENT);
}

__device__ __forceinline__ void waitnb(unsigned* flags, int bx, int by, unsigned v) {
    int t = threadIdx.x;
    if (t < 15) {
        int dx = (t % 3) - 1, dy = (t / 3) - 2;
        int nx = bx + dx, ny = by + dy;
        if (((dx | dy) != 0) && (unsigned)nx < GX && (unsigned)ny < GY) {
            unsigned* f = flags + (size_t)(ny * GX + nx) * FLAG_STRIDE;
            while (__hip_atomic_load(f, __ATOMIC_ACQUIRE,
                                     __HIP_MEMORY_SCOPE_AGENT) < v)
                __builtin_amdgcn_s_sleep(4);
        }
    }
    __syncthreads();   // acquire visible block-wide before any halo read
}

// ======================= cooperative single-kernel path ====================

__global__ __launch_bounds__(256, 5) void k_crf(Params P) {
    __shared__ __align__(16) char smem[SM_BYTES];
    float4* sQ  = (float4*)smem;                    // f1/f2 staging
    float2* s2t = (float2*)smem;                    // s2 staging
    float2* ii0 = (float2*)smem;                    // s1 V-out (region0)
    float*  sG  = (float*)(smem + OFF_R1);          // gray tile (region1)
    float2* ii1 = (float2*)(smem + OFF_R1);         // s2 V-out (region1)
    float4* i0  = (float4*)smem;                    // f1 post-V aliases
    float4* i1  = (float4*)(smem + 6656);
    float4* i2  = (float4*)(smem + OFF_R1);
    float4* ia  = (float4*)(smem + OFF_R1);         // f2 V-out A
    float4* ib  = (float4*)smem;                    // f2 V-out B

    int t = threadIdx.x;
    int L = swz(blockIdx.x, NBLK);
    int bx = L & (GX - 1), by = L >> 4;
    int x0 = bx * TX, y0 = by * TY;
    int row = t >> 5, col = t & 31;
    int py = y0 + row, px = x0 + col;
    int p = py * W + px;
    int vc = t % CIN, vr0 = (t / CIN) * 2;
    int cidx = (row + RAD) * CIN + col + RAD;
    unsigned* flags = P.flags;

    // ---- phase 0: gray + softmax(-unary), TILE-mapped (so the flag of
    //      this block certifies exactly this tile's gray/Q) ----
    float4 u = P.unary[p];
    {
        float r = P.image[3 * p], g = P.image[3 * p + 1], b = P.image[3 * p + 2];
        P.gray[p] = 0.2989f * r + 0.5870f * g + 0.1140f * b;
        float mn = fminf(fminf(u.x, u.y), fminf(u.z, u.w));
        float ex = expf(mn - u.x), ey = expf(mn - u.y);
        float ez = expf(mn - u.z), ew = expf(mn - u.w);
        float inv = 1.f / (ex + ey + ez + ew);
        P.Q[p] = f4(ex * inv, ey * inv, ez * inv, ew * inv);
    }
    float Sgx = 0.f, Sgy = 0.f, Sux = 0.f, Suy = 0.f;
    #pragma unroll
    for (int d = -RAD; d <= RAD; ++d) {
        int xx = px + d, yy = py + d;
        if (xx >= 0 && xx < W) { Sgx += P.wg.w[d + RAD]; Sux += P.wu.w[d + RAD]; }
        if (yy >= 0 && yy < H) { Sgy += P.wg.w[d + RAD]; Suy += P.wu.w[d + RAD]; }
    }
    float s3 = 3.f / (Sgx * Sgy - P.c0g);          // SPATIAL_COMPAT / spatial_norm
    publish(flags, L, 1);
    waitnb(flags, bx, by, 1);                      // gray halo ready

    // ---- s1: conv{gray, gray^2} -> mI, iv (regs); a1b1 -> global ----
    for (int i = t; i < RIN * CIN; i += 256) {
        int r = i / CIN, c = i - r * CIN;
        int gx = x0 + c - RAD, gy = y0 + r - RAD;
        float g = 0.f;
        if ((unsigned)gx < W && (unsigned)gy < H) g = P.gray[gy * W + gx];
        sG[i] = g;
    }
    __syncthreads();
    if (t < NVT) {
        float2 acc0 = make_float2(0.f, 0.f), acc1 = acc0;
        #pragma unroll
        for (int s = 0; s < 22; ++s) {
            float g = sG[(vr0 + s) * CIN + vc];
            if (s <= 20) { float wgv = P.wu.w[s] * g; acc0.x += wgv; acc0.y = fmaf(wgv, g, acc0.y); }
            if (s >= 1)  { float wgv = P.wu.w[s-1] * g; acc1.x += wgv; acc1.y = fmaf(wgv, g, acc1.y); }
        }
        ii0[vr0 * CIN + vc] = acc0;                // region0 (free during s1)
        ii0[(vr0 + 1) * CIN + vc] = acc1;
    }
    __syncthreads();
    float gv = sG[cidx];                           // persists in reg
    float mI, iv, ibn;
    {
        float2 A = make_float2(0.f, 0.f);
        #pragma unroll
        for (int d = 0; d < KS; ++d) {
            float2 v = ii0[row * CIN + col + d];
            A.x = fmaf(P.wu.w[d], v.x, A.x);
            A.y = fmaf(P.wu.w[d], v.y, A.y);
        }
        mI = A.x - P.c0u * gv;
        float mII = A.y - P.c0u * gv * gv;
        iv = 1.f / ((mII - mI * mI) + CRF_EPS);
        float N = Sux * Suy - P.c0u;               // gf(ones)
        float a1v = mI * (1.f - N) * iv;
        float b1v = N - a1v * mI;
        P.a1b1[p] = make_float2(a1v, b1v);
    }
    publish(flags, L, 2);
    waitnb(flags, bx, by, 2);                      // a1b1 halo ready

    // ---- s2: conv a1b1 -> inv_bn (reg) ----
    for (int i = t; i < RIN * CIN; i += 256) {
        int r = i / CIN, c = i - r * CIN;
        int gx = x0 + c - RAD, gy = y0 + r - RAD;
        float2 v = make_float2(0.f, 0.f);
        if ((unsigned)gx < W && (unsigned)gy < H) v = P.a1b1[gy * W + gx];
        s2t[i] = v;
    }
    __syncthreads();
    if (t < NVT) {
        float2 acc0 = make_float2(0.f, 0.f), acc1 = acc0;
        #pragma unroll
        for (int s = 0; s < 22; ++s) {
            float2 v = s2t[(vr0 + s) * CIN + vc];
            if (s <= 20) { acc0.x = fmaf(P.wu.w[s], v.x, acc0.x); acc0.y = fmaf(P.wu.w[s], v.y, acc0.y); }
            if (s >= 1)  { acc1.x = fmaf(P.wu.w[s-1], v.x, acc1.x); acc1.y = fmaf(P.wu.w[s-1], v.y, acc1.y); }
        }
        ii1[vr0 * CIN + vc] = acc0;                // region1 (sG dead; gv in reg)
        ii1[(vr0 + 1) * CIN + vc] = acc1;
    }
    __syncthreads();
    {
        float2 A = make_float2(0.f, 0.f);
        #pragma unroll
        for (int d = 0; d < KS; ++d) {
            float2 v = ii1[row * CIN + col + d];
            A.x = fmaf(P.wu.w[d], v.x, A.x);
            A.y = fmaf(P.wu.w[d], v.y, A.y);
        }
        float2 cen = s2t[cidx];
        float va = A.x - P.c0u * cen.x;
        float vb = A.y - P.c0u * cen.y;
        ibn = 10.f / (va * gv + vb);               // BILATERAL_COMPAT / norm
    }

    // ---- 5 mean-field iterations ----
    // flags: f1(it) publishes 3+2it (a,b written AND Q-halo reads done);
    //        f2(it) publishes 4+2it (Q written AND a,b-halo reads done).
    float px_part, py_part, pz_part, pw_part;
    for (int it = 0; it < 5; ++it) {
        // === f1 ===
        if (it > 0) waitnb(flags, bx, by, 2 + 2 * it);  // nbr f2(it-1): Q halo + a,b WAR
        __syncthreads();                           // region0/1 reads done
        for (int i = t; i < RIN * CIN; i += 256) {
            int r = i / CIN, c = i - r * CIN;
            int gx = x0 + c - RAD, gy = y0 + r - RAD;
            float4 q = f4(0.f, 0.f, 0.f, 0.f); float g = 0.f;
            if ((unsigned)gx < W && (unsigned)gy < H) {
                int pp = gy * W + gx; q = P.Q[pp]; g = P.gray[pp];
            }
            sQ[i] = q; sG[i] = g;                  // re-stage gray each iter
        }
        __syncthreads();
        float4 Qc = sQ[cidx];
        float4 a0[2], a1r[2], a2[2];
        if (t < NVT) {
            #pragma unroll
            for (int j = 0; j < 2; ++j) { a0[j] = f4(0,0,0,0); a1r[j] = a0[j]; a2[j] = a0[j]; }
            #pragma unroll
            for (int s = 0; s < 22; ++s) {
                float4 q = sQ[(vr0 + s) * CIN + vc];
                float g = sG[(vr0 + s) * CIN + vc];
                float4 gq = f4(g * q.x, g * q.y, g * q.z, g * q.w);
                if (s <= 20) {
                    a0[0]  = fma4(P.wg.w[s], q, a0[0]);
                    a1r[0] = fma4(P.wu.w[s], q, a1r[0]);
                    a2[0]  = fma4(P.wu.w[s], gq, a2[0]);
                }
                if (s >= 1) {
                    a0[1]  = fma4(P.wg.w[s-1], q, a0[1]);
                    a1r[1] = fma4(P.wu.w[s-1], q, a1r[1]);
                    a2[1]  = fma4(P.wu.w[s-1], gq, a2[1]);
                }
            }
        }
        __syncthreads();                           // sQ+sG reads done
        if (t < NVT) {
            #pragma unroll
            for (int j = 0; j < 2; ++j) {
                i0[(vr0 + j) * CIN + vc] = a0[j];
                i1[(vr0 + j) * CIN + vc] = a1r[j];
                i2[(vr0 + j) * CIN + vc] = a2[j];   // overwrites sG (dead)
            }
        }
        __syncthreads();
        {
            float4 A0 = f4(0,0,0,0), A1 = A0, A2 = A0;
            #pragma unroll
            for (int d = 0; d < KS; ++d) {
                A0 = fma4(P.wg.w[d], i0[row * CIN + col + d], A0);
                A1 = fma4(P.wu.w[d], i1[row * CIN + col + d], A1);
                A2 = fma4(P.wu.w[d], i2[row * CIN + col + d], A2);
            }
            float4 g4  = fma4(-P.c0g, Qc, A0);
            float4 m4  = fma4(-P.c0u, Qc, A1);
            float4 mi4 = fma4(-P.c0u * gv, Qc, A2);
            float4 a, b;
            a.x = (mi4.x - mI * m4.x) * iv; a.y = (mi4.y - mI * m4.y) * iv;
            a.z = (mi4.z - mI * m4.z) * iv; a.w = (mi4.w - mI * m4.w) * iv;
            b.x = m4.x - a.x * mI; b.y = m4.y - a.y * mI;
            b.z = m4.z - a.z * mI; b.w = m4.w - a.w * mI;
            px_part = fmaf(s3, g4.x, -u.x); py_part = fmaf(s3, g4.y, -u.y);
            pz_part = fmaf(s3, g4.z, -u.z); pw_part = fmaf(s3, g4.w, -u.w);
            P.a_arr[p] = a; P.b_arr[p] = b;
        }
        publish(flags, L, 3 + 2 * it);
        waitnb(flags, bx, by, 3 + 2 * it);         // nbr f1(it): a,b halo + Q WAR

        // === f2 ===
        for (int i = t; i < RIN * CIN; i += 256) {
            int r = i / CIN, c = i - r * CIN;
            int gx = x0 + c - RAD, gy = y0 + r - RAD;
            float4 v = f4(0.f, 0.f, 0.f, 0.f);
            if ((unsigned)gx < W && (unsigned)gy < H) v = P.a_arr[gy * W + gx];
            sQ[i] = v;
        }
        __syncthreads();
        float4 Ac = sQ[cidx];
        if (t < NVT) {
            float4 va0 = f4(0,0,0,0), va1 = va0;
            #pragma unroll
            for (int s = 0; s < 22; ++s) {
                float4 v = sQ[(vr0 + s) * CIN + vc];
                if (s <= 20) va0 = fma4(P.wu.w[s], v, va0);
                if (s >= 1)  va1 = fma4(P.wu.w[s-1], v, va1);
            }
            ia[vr0 * CIN + vc] = va0;              // region1, no clobber of sQ
            ia[(vr0 + 1) * CIN + vc] = va1;
        }
        __syncthreads();                           // sQ(A) reads + ia writes done
        for (int i = t; i < RIN * CIN; i += 256) {
            int r = i / CIN, c = i - r * CIN;
            int gx = x0 + c - RAD, gy = y0 + r - RAD;
            float4 v = f4(0.f, 0.f, 0.f, 0.f);
            if ((unsigned)gx < W && (unsigned)gy < H) v = P.b_arr[gy * W + gx];
            sQ[i] = v;
        }
        __syncthreads();
        float4 Bc = sQ[cidx];
        float4 vb0 = f4(0,0,0,0), vb1 = vb0;
        if (t < NVT) {
            #pragma unroll
            for (int s = 0; s < 22; ++s) {
                float4 v = sQ[(vr0 + s) * CIN + vc];
                if (s <= 20) vb0 = fma4(P.wu.w[s], v, vb0);
                if (s >= 1)  vb1 = fma4(P.wu.w[s-1], v, vb1);
            }
        }
        __syncthreads();                           // sQ(B) reads done
        if (t < NVT) {
            ib[vr0 * CIN + vc] = vb0;              // overwrite region0
            ib[(vr0 + 1) * CIN + vc] = vb1;
        }
        __syncthreads();
        {
            float4 VA = f4(0,0,0,0), VB = VA;
            #pragma unroll
            for (int d = 0; d < KS; ++d) {
                VA = fma4(P.wu.w[d], ia[row * CIN + col + d], VA);
                VB = fma4(P.wu.w[d], ib[row * CIN + col + d], VB);
            }
            float4 a4 = fma4(-P.c0u, Ac, VA);
            float4 b4 = fma4(-P.c0u, Bc, VB);
            float lx = fmaf(fmaf(a4.x, gv, b4.x), ibn, px_part);
            float ly = fmaf(fmaf(a4.y, gv, b4.y), ibn, py_part);
            float lz = fmaf(fmaf(a4.z, gv, b4.z), ibn, pz_part);
            float lw = fmaf(fmaf(a4.w, gv, b4.w), ibn, pw_part);
            float m = fmaxf(fmaxf(lx, ly), fmaxf(lz, lw));
            float ex = expf(lx - m), ey = expf(ly - m);
            float ez = expf(lz - m), ew = expf(lw - m);
            float inv = 1.f / (ex + ey + ez + ew);
            float4 qn = f4(ex * inv, ey * inv, ez * inv, ew * inv);
            if (it == 4) P.Qfinal[p] = qn;
            else         P.Q[p] = qn;
        }
        if (it < 4) publish(flags, L, 4 + 2 * it);
    }
}

// ===================== fallback: proven round-5 multi-dispatch ==============

__global__ __launch_bounds__(256) void fb_init(const float* __restrict__ img,
        const float4* __restrict__ unary, float* __restrict__ gray,
        float4* __restrict__ Q, float* __restrict__ Sg, float* __restrict__ Su,
        W21 wg, W21 wu) {
    int t = threadIdx.x;
    if (blockIdx.x < 2) {
        int x = blockIdx.x * 256 + t;
        float sg = 0.f, su = 0.f;
        #pragma unroll
        for (int d = -RAD; d <= RAD; ++d) {
            int xx = x + d;
            if (xx >= 0 && xx < W) { sg += wg.w[d + RAD]; su += wu.w[d + RAD]; }
        }
        Sg[x] = sg; Su[x] = su;
    }
    int b = swz(blockIdx.x, NPIX / 256);
    int p = b * 256 + t;
    float r = img[3 * p], g = img[3 * p + 1], bch = img[3 * p + 2];
    gray[p] = 0.2989f * r + 0.5870f * g + 0.1140f * bch;
    float4 u = unary[p];
    float mn = fminf(fminf(u.x, u.y), fminf(u.z, u.w));
    float ex = expf(mn - u.x), ey = expf(mn - u.y), ez = expf(mn - u.z), ew = expf(mn - u.w);
    float inv = 1.f / (ex + ey + ez + ew);
    Q[p] = f4(ex * inv, ey * inv, ez * inv, ew * inv);
}

__global__ __launch_bounds__(256, 4) void fb_s1(const float* __restrict__ gray,
        const float* __restrict__ Su, float* __restrict__ mean_I,
        float* __restrict__ inv_var, float2* __restrict__ a1b1,
        W21 wu, float c0u) {
    __shared__ float  sg[RIN][CIN];
    __shared__ float2 ii[TY][CIN];
    int L = swz(blockIdx.x, NBLK);
    int x0 = (L & (GX - 1)) * TX, y0 = (L >> 4) * TY;
    int t = threadIdx.x;
    for (int i = t; i < RIN * CIN; i += 256) {
        int r = i / CIN, c = i - r * CIN;
        int gx = x0 + c - RAD, gy = y0 + r - RAD;
        float g = 0.f;
        if ((unsigned)gx < W && (unsigned)gy < H) g = gray[gy * W + gx];
        sg[r][c] = g;
    }
    __syncthreads();
    if (t < NVT) {
        int c = t % CIN, r0 = (t / CIN) * 2;
        float2 acc0 = make_float2(0.f, 0.f), acc1 = acc0;
        #pragma unroll
        for (int s = 0; s < 22; ++s) {
            float g = sg[r0 + s][c];
            if (s <= 20) { float wgv = wu.w[s] * g; acc0.x += wgv; acc0.y = fmaf(wgv, g, acc0.y); }
            if (s >= 1)  { float wgv = wu.w[s-1] * g; acc1.x += wgv; acc1.y = fmaf(wgv, g, acc1.y); }
        }
        ii[r0][c] = acc0; ii[r0 + 1][c] = acc1;
    }
    __syncthreads();
    int row = t >> 5, col = t & 31;
    float2 A = make_float2(0.f, 0.f);
    #pragma unroll
    for (int d = 0; d < KS; ++d) {
        float2 v = ii[row][col + d];
        A.x = fmaf(wu.w[d], v.x, A.x);
        A.y = fmaf(wu.w[d], v.y, A.y);
    }
    int py = y0 + row, px = x0 + col;
    int p = py * W + px;
    float gc = sg[row + RAD][col + RAD];
    float mI = A.x - c0u * gc;
    float mII = A.y - c0u * gc * gc;
    float iv = 1.f / ((mII - mI * mI) + CRF_EPS);
    float N = Su[px] * Su[py] - c0u;
    float av = mI * (1.f - N) * iv;
    float bv = N - av * mI;
    mean_I[p] = mI; inv_var[p] = iv; a1b1[p] = make_float2(av, bv);
}

__global__ __launch_bounds__(256, 4) void fb_s2(const float2* __restrict__ a1b1,
        const float* __restrict__ gray, float* __restrict__ inv_bn,
        W21 wu, float c0u) {
    __shared__ float2 s2[RIN][CIN];
    __shared__ float2 ii[TY][CIN];
    int L = swz(blockIdx.x, NBLK);
    int x0 = (L & (GX - 1)) * TX, y0 = (L >> 4) * TY;
    int t = threadIdx.x;
    for (int i = t; i < RIN * CIN; i += 256) {
        int r = i / CIN, c = i - r * CIN;
        int gx = x0 + c - RAD, gy = y0 + r - RAD;
        float2 v = make_float2(0.f, 0.f);
        if ((unsigned)gx < W && (unsigned)gy < H) v = a1b1[gy * W + gx];
        s2[r][c] = v;
    }
    __syncthreads();
    if (t < NVT) {
        int c = t % CIN, r0 = (t / CIN) * 2;
        float2 acc0 = make_float2(0.f, 0.f), acc1 = acc0;
        #pragma unroll
        for (int s = 0; s < 22; ++s) {
            float2 v = s2[r0 + s][c];
            if (s <= 20) { acc0.x = fmaf(wu.w[s], v.x, acc0.x); acc0.y = fmaf(wu.w[s], v.y, acc0.y); }
            if (s >= 1)  { acc1.x = fmaf(wu.w[s-1], v.x, acc1.x); acc1.y = fmaf(wu.w[s-1], v.y, acc1.y); }
        }
        ii[r0][c] = acc0; ii[r0 + 1][c] = acc1;
    }
    __syncthreads();
    int row = t >> 5, col = t & 31;
    float2 A = make_float2(0.f, 0.f);
    #pragma unroll
    for (int d = 0; d < KS; ++d) {
        float2 v = ii[row][col + d];
        A.x = fmaf(wu.w[d], v.x, A.x);
        A.y = fmaf(wu.w[d], v.y, A.y);
    }
    int p = (y0 + row) * W + x0 + col;
    float2 cen = s2[row + RAD][col + RAD];
    float va = A.x - c0u * cen.x;
    float vb = A.y - c0u * cen.y;
    inv_bn[p] = 1.f / (va * gray[p] + vb);
}

__global__ __launch_bounds__(256, 4) void fb_f1(const float4* __restrict__ Q,
        const float* __restrict__ gray, const float* __restrict__ mean_I,
        const float* __restrict__ inv_var, const float* __restrict__ Sg,
        const float4* __restrict__ unary, float4* __restrict__ a_out,
        float4* __restrict__ b_out, float4* __restrict__ partial,
        W21 wg, W21 wu, float c0g, float c0u) {
    __shared__ __align__(16) char smem[23296 + 5824 + 6656];
    float4* sQ = (float4*)smem;
    float*  sG = (float*)(smem + 23296);
    float4* i2 = (float4*)(smem + 23296 + 5824);
    float4* i0 = (float4*)smem;
    float4* i1 = (float4*)(smem + 6656);
    int L = swz(blockIdx.x, NBLK);
    int x0 = (L & (GX - 1)) * TX, y0 = (L >> 4) * TY;
    int t = threadIdx.x;
    for (int i = t; i < RIN * CIN; i += 256) {
        int r = i / CIN, c = i - r * CIN;
        int gx = x0 + c - RAD, gy = y0 + r - RAD;
        float4 q = f4(0.f, 0.f, 0.f, 0.f); float g = 0.f;
        if ((unsigned)gx < W && (unsigned)gy < H) {
            int p = gy * W + gx; q = Q[p]; g = gray[p];
        }
        sQ[i] = q; sG[i] = g;
    }
    __syncthreads();
    int row = t >> 5, col = t & 31;
    int py = y0 + row, px = x0 + col;
    int p = py * W + px;
    float mI = mean_I[p], iv = inv_var[p];
    float4 u = unary[p];
    float sgx = Sg[px], sgy = Sg[py];
    float4 Qc = sQ[(row + RAD) * CIN + col + RAD];
    float  gc = sG[(row + RAD) * CIN + col + RAD];
    float4 a0[2], a1[2], a2[2];
    int vc = t % CIN, vr0 = (t / CIN) * 2;
    if (t < NVT) {
        #pragma unroll
        for (int j = 0; j < 2; ++j) { a0[j] = f4(0,0,0,0); a1[j] = a0[j]; a2[j] = a0[j]; }
        #pragma unroll
        for (int s = 0; s < 22; ++s) {
            float4 q = sQ[(vr0 + s) * CIN + vc];
            float g = sG[(vr0 + s) * CIN + vc];
            float4 gq = f4(g * q.x, g * q.y, g * q.z, g * q.w);
            if (s <= 20) {
                a0[0] = fma4(wg.w[s], q, a0[0]);
                a1[0] = fma4(wu.w[s], q, a1[0]);
                a2[0] = fma4(wu.w[s], gq, a2[0]);
            }
            if (s >= 1) {
                a0[1] = fma4(wg.w[s-1], q, a0[1]);
                a1[1] = fma4(wu.w[s-1], q, a1[1]);
                a2[1] = fma4(wu.w[s-1], gq, a2[1]);
            }
        }
    }
    __syncthreads();
    if (t < NVT) {
        #pragma unroll
        for (int j = 0; j < 2; ++j) {
            i0[(vr0 + j) * CIN + vc] = a0[j];
            i1[(vr0 + j) * CIN + vc] = a1[j];
            i2[(vr0 + j) * CIN + vc] = a2[j];
        }
    }
    __syncthreads();
    float4 A0 = f4(0,0,0,0), A1 = A0, A2 = A0;
    #pragma unroll
    for (int d = 0; d < KS; ++d) {
        A0 = fma4(wg.w[d], i0[row * CIN + col + d], A0);
        A1 = fma4(wu.w[d], i1[row * CIN + col + d], A1);
        A2 = fma4(wu.w[d], i2[row * CIN + col + d], A2);
    }
    float4 g4  = fma4(-c0g, Qc, A0);
    float4 m4  = fma4(-c0u, Qc, A1);
    float4 mi4 = fma4(-c0u * gc, Qc, A2);
    float4 a, b;
    a.x = (mi4.x - mI * m4.x) * iv; a.y = (mi4.y - mI * m4.y) * iv;
    a.z = (mi4.z - mI * m4.z) * iv; a.w = (mi4.w - mI * m4.w) * iv;
    b.x = m4.x - a.x * mI; b.y = m4.y - a.y * mI;
    b.z = m4.z - a.z * mI; b.w = m4.w - a.w * mI;
    float s3 = 3.f / (sgx * sgy - c0g);
    float4 part = f4(fmaf(s3, g4.x, -u.x), fmaf(s3, g4.y, -u.y),
                     fmaf(s3, g4.z, -u.z), fmaf(s3, g4.w, -u.w));
    a_out[p] = a; b_out[p] = b; partial[p] = part;
}

__global__ __launch_bounds__(256, 4) void fb_f2(const float4* __restrict__ A,
        const float4* __restrict__ B, const float4* __restrict__ partial,
        const float* __restrict__ gray, const float* __restrict__ inv_bn,
        float4* __restrict__ Qout, W21 wu, float c0u) {
    __shared__ __align__(16) char smem[23296 + 6656];
    float4* sT = (float4*)smem;
    float4* ia = (float4*)(smem + 23296);
    float4* ib = (float4*)smem;
    int L = swz(blockIdx.x, NBLK);
    int x0 = (L & (GX - 1)) * TX, y0 = (L >> 4) * TY;
    int t = threadIdx.x;
    int row = t >> 5, col = t & 31;
    int py = y0 + row, px = x0 + col;
    int p = py * W + px;
    int vc = t % CIN, vr0 = (t / CIN) * 2;
    float gv = gray[p];
    float ibn = 10.f * inv_bn[p];
    float4 part = partial[p];
    for (int i = t; i < RIN * CIN; i += 256) {
        int r = i / CIN, c = i - r * CIN;
        int gx = x0 + c - RAD, gy = y0 + r - RAD;
        float4 v = f4(0.f, 0.f, 0.f, 0.f);
        if ((unsigned)gx < W && (unsigned)gy < H) v = A[gy * W + gx];
        sT[i] = v;
    }
    __syncthreads();
    float4 Ac = sT[(row + RAD) * CIN + col + RAD];
    float4 va0 = f4(0,0,0,0), va1 = va0;
    if (t < NVT) {
        #pragma unroll
        for (int s = 0; s < 22; ++s) {
            float4 v = sT[(vr0 + s) * CIN + vc];
            if (s <= 20) va0 = fma4(wu.w[s], v, va0);
            if (s >= 1)  va1 = fma4(wu.w[s-1], v, va1);
        }
        ia[vr0 * CIN + vc] = va0;
        ia[(vr0 + 1) * CIN + vc] = va1;
    }
    __syncthreads();
    for (int i = t; i < RIN * CIN; i += 256) {
        int r = i / CIN, c = i - r * CIN;
        int gx = x0 + c - RAD, gy = y0 + r - RAD;
        float4 v = f4(0.f, 0.f, 0.f, 0.f);
        if ((unsigned)gx < W && (unsigned)gy < H) v = B[gy * W + gx];
        sT[i] = v;
    }
    __syncthreads();
    float4 Bc = sT[(row + RAD) * CIN + col + RAD];
    float4 vb0 = f4(0,0,0,0), vb1 = vb0;
    if (t < NVT) {
        #pragma unroll
        for (int s = 0; s < 22; ++s) {
            float4 v = sT[(vr0 + s) * CIN + vc];
            if (s <= 20) vb0 = fma4(wu.w[s], v, vb0);
            if (s >= 1)  vb1 = fma4(wu.w[s-1], v, vb1);
        }
    }
    __syncthreads();
    if (t < NVT) {
        ib[vr0 * CIN + vc] = vb0;
        ib[(vr0 + 1) * CIN + vc] = vb1;
    }
    __syncthreads();
    float4 VA = f4(0,0,0,0), VB = VA;
    #pragma unroll
    for (int d = 0; d < KS; ++d) {
        VA = fma4(wu.w[d], ia[row * CIN + col + d], VA);
        VB = fma4(wu.w[d], ib[row * CIN + col + d], VB);
    }
    float4 a4 = fma4(-c0u, Ac, VA);
    float4 b4 = fma4(-c0u, Bc, VB);
    float lx = fmaf(fmaf(a4.x, gv, b4.x), ibn, part.x);
    float ly = fmaf(fmaf(a4.y, gv, b4.y), ibn, part.y);
    float lz = fmaf(fmaf(a4.z, gv, b4.z), ibn, part.z);
    float lw = fmaf(fmaf(a4.w, gv, b4.w), ibn, part.w);
    float m = fmaxf(fmaxf(lx, ly), fmaxf(lz, lw));
    float ex = expf(lx - m), ey = expf(ly - m), ez = expf(lz - m), ew = expf(lw - m);
    float inv = 1.f / (ex + ey + ez + ew);
    Qout[p] = f4(ex * inv, ey * inv, ez * inv, ew * inv);
}

// ---- host ----

static void make_w_host(double theta, W21* w, float* c0) {
    double tmp[KS], s = 0.0;
    for (int d = -RAD; d <= RAD; ++d) {
        double v = exp(-(double)(d * d) / (2.0 * theta * theta));
        tmp[d + RAD] = v; s += v;
    }
    for (int i = 0; i < KS; ++i) w->w[i] = (float)(tmp[i] / s);
    *c0 = (float)(1.0 / (s * s));   // normalized 2D center weight
}

extern "C" void kernel_launch(void* const* d_in, const int* in_sizes, int n_in,
                              void* d_out, int out_size, void* d_ws, size_t ws_size,
                              hipStream_t stream) {
    const float4* unary = (const float4*)d_in[0];
    const float* image = (const float*)d_in[1];
    float* wsf = (float*)d_ws;

    float*  gray    = wsf;
    float*  mean_I  = wsf + 262144;   // coop path reuses this region for flags
    float*  inv_var = wsf + 524288;
    float2* a1b1    = (float2*)(wsf + 786432);
    float*  inv_bn  = wsf + 1310720;
    float*  Sg      = wsf + 1572864;
    float*  Su      = wsf + 1573376;
    float4* Q       = (float4*)(wsf + 1573888);
    float4* partial = (float4*)(wsf + 2622464);
    float4* a_arr   = (float4*)(wsf + 3671040);
    float4* b_arr   = (float4*)(wsf + 4719616);
    unsigned* flags = (unsigned*)(wsf + 262144);   // 1024 * 128 B = 128 KiB < 1 MiB region

    W21 wg, wu; float c0g, c0u;
    make_w_host(2.5, &wg, &c0g);
    make_w_host(10.0 / 3.0, &wu, &c0u);

    // deterministic cooperative-capacity pre-check (host-only, capture-safe)
    int dev = 0;
    (void)hipGetDevice(&dev);
    int coop = 0, nCU = 0, blkPerCU = 0;
    (void)hipDeviceGetAttribute(&coop, hipDeviceAttributeCooperativeLaunch, dev);
    (void)hipDeviceGetAttribute(&nCU, hipDeviceAttributeMultiprocessorCount, dev);
    (void)hipOccupancyMaxActiveBlocksPerMultiprocessor(&blkPerCU,
            (const void*)k_crf, 256, 0);
    bool useCoop = (coop != 0) && ((long)blkPerCU * nCU >= NBLK);

    hipError_t st = hipErrorUnknown;
    if (useCoop) {
        // reset neighbor-sync flags (stream-ordered, graph-capture-safe)
        (void)hipMemsetAsync(flags, 0, (size_t)NBLK * FLAG_STRIDE * sizeof(unsigned),
                             stream);
        Params P;
        P.unary = unary; P.image = image; P.gray = gray; P.Q = Q;
        P.a1b1 = a1b1; P.a_arr = a_arr; P.b_arr = b_arr;
        P.Qfinal = (float4*)d_out; P.flags = flags;
        P.wg = wg; P.wu = wu; P.c0g = c0g; P.c0u = c0u;
        void* args[] = { &P };
        st = hipLaunchCooperativeKernel((const void*)k_crf, dim3(NBLK), dim3(256),
                                        args, 0, stream);
    }
    if (st != hipSuccess) {
        dim3 bl(256), grEl(NPIX / 256), grT(NBLK);
        fb_init<<<grEl, bl, 0, stream>>>(image, unary, gray, Q, Sg, Su, wg, wu);
        fb_s1<<<grT, bl, 0, stream>>>(gray, Su, mean_I, inv_var, a1b1, wu, c0u);
        fb_s2<<<grT, bl, 0, stream>>>(a1b1, gray, inv_bn, wu, c0u);
        for (int it = 0; it < 5; ++it) {
            fb_f1<<<grT, bl, 0, stream>>>(Q, gray, mean_I, inv_var, Sg,
                                          unary, a_arr, b_arr, partial, wg, wu, c0g, c0u);
            float4* qdst = (it == 4) ? (float4*)d_out : Q;
            fb_f2<<<grT, bl, 0, stream>>>(a_arr, b_arr, partial, gray, inv_bn, qdst,
                                          wu, c0u);
        }
    }
}

// Round 2
// 170.237 us; speedup vs baseline: 1.0028x; 1.0011x over previous
//
#include <hip/hip_runtime.h>
#include <math.h>

#define W 512
#define H 512
#define NPIX (W*H)
#define RAD 10
#define KS 21
#define CRF_EPS 1e-4f

// tile geometry: TX x TY outputs per block, halo RAD each side
#define TX 32
#define TY 8
#define CIN (TX + 2*RAD)   // 52
#define RIN (TY + 2*RAD)   // 28
#define GX (W / TX)        // 16
#define GY (H / TY)        // 64
#define NBLK (GX*GY)       // 1024 blocks
#define NVT (CIN * 4)      // (fallback kernels only)

// Cooperative-kernel LDS (35,776 B => 4 blocks/CU):
//  region0 [0, 23296): staging sQ/s2t; post-V plane-split fields
//                      i0 [0,6656) i1 [6656,13312) i2 [13312,19968);
//                      ib [0,6656); s1 ii0 [0,3328)
//  sG      [23296, 29120): persistent gray halo tile (whole kernel)
//  region2 [29120, 35776): ia (f2) / ii1 (s2)
// Every intermediate field is stored as E/O planes (even/odd column),
// 8 rows x 26 cols each; float4 plane stride = 208 float4s, float2 = 208.
#define SM_BYTES 35776
#define OFF_SG 23296
#define OFF_R2 29120

// neighbor-sync flags: one 128B-strided slot per logical tile
#define FLAG_STRIDE 32     // in u32 units => 128 B per flag

struct W21 { float w[KS]; };

struct Params {
    const float4* unary;
    const float*  image;
    float*  gray;
    float4* Q;
    float2* a1b1;
    float4* a_arr;
    float4* b_arr;
    float4* Qfinal;
    unsigned* flags;
    W21 wg, wu;
    float c0g, c0u;
};

__device__ __forceinline__ float4 f4(float x, float y, float z, float w_) {
    return make_float4(x, y, z, w_);
}
__device__ __forceinline__ float4 fma4(float s, float4 a, float4 acc) {
    acc.x = fmaf(s, a.x, acc.x); acc.y = fmaf(s, a.y, acc.y);
    acc.z = fmaf(s, a.z, acc.z); acc.w = fmaf(s, a.w, acc.w);
    return acc;
}
__device__ __forceinline__ int swz(int b, int N) {
    return (b & 7) * (N >> 3) + (b >> 3);
}

// ---- producer/consumer neighborhood sync (replaces grid.sync) ----
__device__ __forceinline__ void publish(unsigned* flags, int L, unsigned v) {
    __syncthreads();   // all lanes' reads+writes of this phase done
    if (threadIdx.x == 0)
        __hip_atomic_store(flags + (size_t)L * FLAG_STRIDE, v,
                           __ATOMIC_RELEASE, __HIP_MEMORY_SCOPE_AGENT);
}

__device__ __forceinline__ void waitnb(unsigned* flags, int bx, int by, unsigned v) {
    int t = threadIdx.x;
    if (t < 15) {
        int dx = (t % 3) - 1, dy = (t / 3) - 2;
        int nx = bx + dx, ny = by + dy;
        if (((dx | dy) != 0) && (unsigned)nx < GX && (unsigned)ny < GY) {
            unsigned* f = flags + (size_t)(ny * GX + nx) * FLAG_STRIDE;
            while (__hip_atomic_load(f, __ATOMIC_ACQUIRE,
                                     __HIP_MEMORY_SCOPE_AGENT) < v)
                __builtin_amdgcn_s_sleep(2);
        }
    }
    __syncthreads();   // acquire visible block-wide before any halo read
}

// ======================= cooperative single-kernel path ====================

__global__ __launch_bounds__(256, 4) void k_crf(Params P) {
    __shared__ __align__(16) char smem[SM_BYTES];
    float4* sQ  = (float4*)smem;                    // f1/f2 staging
    float2* s2t = (float2*)smem;                    // s2 staging
    float*  sG  = (float*)(smem + OFF_SG);          // PERSISTENT gray tile
    // plane-split fields: E base; O = E + 208 (elements)
    float4* i0E = (float4*)smem;                    // f1 wg-field
    float4* i1E = (float4*)(smem + 6656);           // f1 wu-field (q)
    float4* i2E = (float4*)(smem + 13312);          // f1 wu-field (g*q)
    float4* iaE = (float4*)(smem + OFF_R2);         // f2 A field
    float4* ibE = (float4*)smem;                    // f2 B field
    float2* ii0E = (float2*)smem;                   // s1 field
    float2* ii1E = (float2*)(smem + OFF_R2);        // s2 field

    int t = threadIdx.x;
    int L = swz(blockIdx.x, NBLK);
    int bx = L & (GX - 1), by = L >> 4;
    int x0 = bx * TX, y0 = by * TY;
    // phase-0 per-thread pixel (1 px/thread, tile mapped)
    int row = t >> 5, col = t & 31;
    int p = (y0 + row) * W + x0 + col;
    // V mapping: 104 threads, 4 rows each
    int vc = t % CIN, vr4 = (t / CIN) * 4;
    // H/epilogue mapping: 128 threads, 2 adjacent cols each
    int hrow = t >> 4, hm = t & 15;
    int c0 = 2 * hm;
    int hpy = y0 + hrow;
    int p0 = hpy * W + x0 + c0, p1 = p0 + 1;
    int cidx0 = (hrow + RAD) * CIN + c0 + RAD;
    int cidx1 = cidx0 + 1;
    int hb = hrow * 26 + hm;
    unsigned* flags = P.flags;

    // ---- phase 0: gray + softmax(-unary), tile-mapped ----
    {
        float r = P.image[3 * p], g = P.image[3 * p + 1], b = P.image[3 * p + 2];
        P.gray[p] = 0.2989f * r + 0.5870f * g + 0.1140f * b;
        float4 uu = P.unary[p];
        float mn = fminf(fminf(uu.x, uu.y), fminf(uu.z, uu.w));
        float ex = expf(mn - uu.x), ey = expf(mn - uu.y);
        float ez = expf(mn - uu.z), ew = expf(mn - uu.w);
        float inv = 1.f / (ex + ey + ez + ew);
        P.Q[p] = f4(ex * inv, ey * inv, ez * inv, ew * inv);
    }
    // per-epilogue-pixel constants (threads < 128 own 2 pixels)
    float4 u0, u1; float s30, s31, N0, N1;
    if (t < 128) {
        u0 = P.unary[p0]; u1 = P.unary[p1];
        float Sgy = 0.f, Suy = 0.f, Sgx0 = 0.f, Sux0 = 0.f, Sgx1 = 0.f, Sux1 = 0.f;
        #pragma unroll
        for (int d = -RAD; d <= RAD; ++d) {
            int yy = hpy + d;
            if ((unsigned)yy < H) { Sgy += P.wg.w[d + RAD]; Suy += P.wu.w[d + RAD]; }
            int xa = x0 + c0 + d;
            if ((unsigned)xa < W) { Sgx0 += P.wg.w[d + RAD]; Sux0 += P.wu.w[d + RAD]; }
            int xb = xa + 1;
            if ((unsigned)xb < W) { Sgx1 += P.wg.w[d + RAD]; Sux1 += P.wu.w[d + RAD]; }
        }
        s30 = 3.f / (Sgx0 * Sgy - P.c0g);
        s31 = 3.f / (Sgx1 * Sgy - P.c0g);
        N0 = Sux0 * Suy - P.c0u;
        N1 = Sux1 * Suy - P.c0u;
    }
    publish(flags, L, 1);
    waitnb(flags, bx, by, 1);                      // gray halo ready

    // ---- s1: conv{gray, gray^2}; sG staged ONCE, persists all iterations ----
    for (int i = t; i < RIN * CIN; i += 256) {
        int r = i / CIN, c = i - r * CIN;
        int gx = x0 + c - RAD, gy = y0 + r - RAD;
        float g = 0.f;
        if ((unsigned)gx < W && (unsigned)gy < H) g = P.gray[gy * W + gx];
        sG[i] = g;
    }
    __syncthreads();
    {
        float2 A[4];
        if (t < 104) {
            #pragma unroll
            for (int j = 0; j < 4; ++j) A[j] = make_float2(0.f, 0.f);
            #pragma unroll
            for (int s = 0; s < 24; ++s) {
                float g = sG[(vr4 + s) * CIN + vc];
                #pragma unroll
                for (int j = 0; j < 4; ++j) {
                    int d = s - j;
                    if (d >= 0 && d <= 20) {
                        float wgv = P.wu.w[d] * g;
                        A[j].x += wgv; A[j].y = fmaf(wgv, g, A[j].y);
                    }
                }
            }
        }
        __syncthreads();
        if (t < 104) {
            float2* pl = ii0E + (vc & 1) * 208;
            #pragma unroll
            for (int j = 0; j < 4; ++j) pl[(vr4 + j) * 26 + (vc >> 1)] = A[j];
        }
        __syncthreads();
    }
    float gv0 = 0.f, gv1 = 0.f, mI0, mI1, iv0, iv1, ibn0, ibn1;
    if (t < 128) {
        gv0 = sG[cidx0]; gv1 = sG[cidx1];
        float2 a0 = make_float2(0.f, 0.f), a1 = a0;
        #pragma unroll
        for (int k = 0; k <= 10; ++k) {
            float2 e = ii0E[hb + k], o = ii0E[208 + hb + k];
            float we = P.wu.w[2 * k];
            a0.x = fmaf(we, e.x, a0.x); a0.y = fmaf(we, e.y, a0.y);
            a1.x = fmaf(we, o.x, a1.x); a1.y = fmaf(we, o.y, a1.y);
            if (k < 10) {
                float wo = P.wu.w[2 * k + 1];
                a0.x = fmaf(wo, o.x, a0.x); a0.y = fmaf(wo, o.y, a0.y);
            }
            if (k > 0) {
                float wp = P.wu.w[2 * k - 1];
                a1.x = fmaf(wp, e.x, a1.x); a1.y = fmaf(wp, e.y, a1.y);
            }
        }
        mI0 = a0.x - P.c0u * gv0;
        float mII0 = a0.y - P.c0u * gv0 * gv0;
        iv0 = 1.f / ((mII0 - mI0 * mI0) + CRF_EPS);
        float av0 = mI0 * (1.f - N0) * iv0;
        P.a1b1[p0] = make_float2(av0, N0 - av0 * mI0);
        mI1 = a1.x - P.c0u * gv1;
        float mII1 = a1.y - P.c0u * gv1 * gv1;
        iv1 = 1.f / ((mII1 - mI1 * mI1) + CRF_EPS);
        float av1 = mI1 * (1.f - N1) * iv1;
        P.a1b1[p1] = make_float2(av1, N1 - av1 * mI1);
    }
    publish(flags, L, 2);
    waitnb(flags, bx, by, 2);                      // a1b1 halo ready

    // ---- s2: conv a1b1 -> inv_bn (regs) ----
    for (int i = t; i < RIN * CIN; i += 256) {
        int r = i / CIN, c = i - r * CIN;
        int gx = x0 + c - RAD, gy = y0 + r - RAD;
        float2 v = make_float2(0.f, 0.f);
        if ((unsigned)gx < W && (unsigned)gy < H) v = P.a1b1[gy * W + gx];
        s2t[i] = v;
    }
    __syncthreads();
    {
        float2 A[4];
        if (t < 104) {
            #pragma unroll
            for (int j = 0; j < 4; ++j) A[j] = make_float2(0.f, 0.f);
            #pragma unroll
            for (int s = 0; s < 24; ++s) {
                float2 v = s2t[(vr4 + s) * CIN + vc];
                #pragma unroll
                for (int j = 0; j < 4; ++j) {
                    int d = s - j;
                    if (d >= 0 && d <= 20) {
                        float w_ = P.wu.w[d];
                        A[j].x = fmaf(w_, v.x, A[j].x);
                        A[j].y = fmaf(w_, v.y, A[j].y);
                    }
                }
            }
        }
        __syncthreads();
        if (t < 104) {
            float2* pl = ii1E + (vc & 1) * 208;
            #pragma unroll
            for (int j = 0; j < 4; ++j) pl[(vr4 + j) * 26 + (vc >> 1)] = A[j];
        }
        __syncthreads();
    }
    if (t < 128) {
        float2 a0 = make_float2(0.f, 0.f), a1 = a0;
        #pragma unroll
        for (int k = 0; k <= 10; ++k) {
            float2 e = ii1E[hb + k], o = ii1E[208 + hb + k];
            float we = P.wu.w[2 * k];
            a0.x = fmaf(we, e.x, a0.x); a0.y = fmaf(we, e.y, a0.y);
            a1.x = fmaf(we, o.x, a1.x); a1.y = fmaf(we, o.y, a1.y);
            if (k < 10) {
                float wo = P.wu.w[2 * k + 1];
                a0.x = fmaf(wo, o.x, a0.x); a0.y = fmaf(wo, o.y, a0.y);
            }
            if (k > 0) {
                float wp = P.wu.w[2 * k - 1];
                a1.x = fmaf(wp, e.x, a1.x); a1.y = fmaf(wp, e.y, a1.y);
            }
        }
        float2 cen0 = s2t[cidx0], cen1 = s2t[cidx1];
        float va0 = a0.x - P.c0u * cen0.x, vb0 = a0.y - P.c0u * cen0.y;
        ibn0 = 10.f / (va0 * gv0 + vb0);
        float va1 = a1.x - P.c0u * cen1.x, vb1 = a1.y - P.c0u * cen1.y;
        ibn1 = 10.f / (va1 * gv1 + vb1);
    }

    // ---- 5 mean-field iterations ----
    float4 part0, part1;
    for (int it = 0; it < 5; ++it) {
        // === f1 ===
        if (it > 0) waitnb(flags, bx, by, 2 + 2 * it);  // nbr f2(it-1)
        __syncthreads();                           // region0 reads done
        for (int i = t; i < RIN * CIN; i += 256) {
            int r = i / CIN, c = i - r * CIN;
            int gx = x0 + c - RAD, gy = y0 + r - RAD;
            float4 q = f4(0.f, 0.f, 0.f, 0.f);
            if ((unsigned)gx < W && (unsigned)gy < H) q = P.Q[gy * W + gx];
            sQ[i] = q;                             // gray persists in sG
        }
        __syncthreads();
        float4 Qc0, Qc1;
        if (t < 128) { Qc0 = sQ[cidx0]; Qc1 = sQ[cidx1]; }
        {
            float4 A0[4], A1[4], A2[4];
            if (t < 104) {
                #pragma unroll
                for (int j = 0; j < 4; ++j) {
                    A0[j] = f4(0,0,0,0); A1[j] = A0[j]; A2[j] = A0[j];
                }
                #pragma unroll
                for (int s = 0; s < 24; ++s) {
                    float4 q = sQ[(vr4 + s) * CIN + vc];
                    float g = sG[(vr4 + s) * CIN + vc];
                    float4 gq = f4(g * q.x, g * q.y, g * q.z, g * q.w);
                    #pragma unroll
                    for (int j = 0; j < 4; ++j) {
                        int d = s - j;
                        if (d >= 0 && d <= 20) {
                            A0[j] = fma4(P.wg.w[d], q, A0[j]);
                            A1[j] = fma4(P.wu.w[d], q, A1[j]);
                            A2[j] = fma4(P.wu.w[d], gq, A2[j]);
                        }
                    }
                }
            }
            __syncthreads();                       // Qc + V reads of sQ done
            if (t < 104) {
                int pb = (vc & 1) * 208, ci = vc >> 1;
                #pragma unroll
                for (int j = 0; j < 4; ++j) {
                    int rw = (vr4 + j) * 26 + ci;
                    i0E[pb + rw] = A0[j];
                    i1E[pb + rw] = A1[j];
                    i2E[pb + rw] = A2[j];
                }
            }
            __syncthreads();
        }
        if (t < 128) {
            float4 G0 = f4(0,0,0,0), G1 = G0, M0 = G0, M1 = G0, X0 = G0, X1 = G0;
            #pragma unroll
            for (int k = 0; k <= 10; ++k) {
                float4 e0 = i0E[hb + k], o0 = i0E[208 + hb + k];
                float4 e1 = i1E[hb + k], o1 = i1E[208 + hb + k];
                float4 e2 = i2E[hb + k], o2 = i2E[208 + hb + k];
                float wge = P.wg.w[2 * k], wue = P.wu.w[2 * k];
                G0 = fma4(wge, e0, G0);  G1 = fma4(wge, o0, G1);
                M0 = fma4(wue, e1, M0);  M1 = fma4(wue, o1, M1);
                X0 = fma4(wue, e2, X0);  X1 = fma4(wue, o2, X1);
                if (k < 10) {
                    float wgo = P.wg.w[2 * k + 1], wuo = P.wu.w[2 * k + 1];
                    G0 = fma4(wgo, o0, G0);
                    M0 = fma4(wuo, o1, M0);
                    X0 = fma4(wuo, o2, X0);
                }
                if (k > 0) {
                    float wgp = P.wg.w[2 * k - 1], wup = P.wu.w[2 * k - 1];
                    G1 = fma4(wgp, e0, G1);
                    M1 = fma4(wup, e1, M1);
                    X1 = fma4(wup, e2, X1);
                }
            }
            // pixel 0
            {
                float4 g4  = fma4(-P.c0g, Qc0, G0);
                float4 m4  = fma4(-P.c0u, Qc0, M0);
                float4 mi4 = fma4(-P.c0u * gv0, Qc0, X0);
                float4 a, b;
                a.x = (mi4.x - mI0 * m4.x) * iv0; a.y = (mi4.y - mI0 * m4.y) * iv0;
                a.z = (mi4.z - mI0 * m4.z) * iv0; a.w = (mi4.w - mI0 * m4.w) * iv0;
                b.x = m4.x - a.x * mI0; b.y = m4.y - a.y * mI0;
                b.z = m4.z - a.z * mI0; b.w = m4.w - a.w * mI0;
                part0 = f4(fmaf(s30, g4.x, -u0.x), fmaf(s30, g4.y, -u0.y),
                           fmaf(s30, g4.z, -u0.z), fmaf(s30, g4.w, -u0.w));
                P.a_arr[p0] = a; P.b_arr[p0] = b;
            }
            // pixel 1
            {
                float4 g4  = fma4(-P.c0g, Qc1, G1);
                float4 m4  = fma4(-P.c0u, Qc1, M1);
                float4 mi4 = fma4(-P.c0u * gv1, Qc1, X1);
                float4 a, b;
                a.x = (mi4.x - mI1 * m4.x) * iv1; a.y = (mi4.y - mI1 * m4.y) * iv1;
                a.z = (mi4.z - mI1 * m4.z) * iv1; a.w = (mi4.w - mI1 * m4.w) * iv1;
                b.x = m4.x - a.x * mI1; b.y = m4.y - a.y * mI1;
                b.z = m4.z - a.z * mI1; b.w = m4.w - a.w * mI1;
                part1 = f4(fmaf(s31, g4.x, -u1.x), fmaf(s31, g4.y, -u1.y),
                           fmaf(s31, g4.z, -u1.z), fmaf(s31, g4.w, -u1.w));
                P.a_arr[p1] = a; P.b_arr[p1] = b;
            }
        }
        publish(flags, L, 3 + 2 * it);
        waitnb(flags, bx, by, 3 + 2 * it);         // nbr f1(it): a,b halo

        // === f2 ===
        for (int i = t; i < RIN * CIN; i += 256) {
            int r = i / CIN, c = i - r * CIN;
            int gx = x0 + c - RAD, gy = y0 + r - RAD;
            float4 v = f4(0.f, 0.f, 0.f, 0.f);
            if ((unsigned)gx < W && (unsigned)gy < H) v = P.a_arr[gy * W + gx];
            sQ[i] = v;
        }
        __syncthreads();
        float4 Ac0, Ac1;
        if (t < 128) { Ac0 = sQ[cidx0]; Ac1 = sQ[cidx1]; }
        if (t < 104) {
            float4 VA[4];
            #pragma unroll
            for (int j = 0; j < 4; ++j) VA[j] = f4(0,0,0,0);
            #pragma unroll
            for (int s = 0; s < 24; ++s) {
                float4 v = sQ[(vr4 + s) * CIN + vc];
                #pragma unroll
                for (int j = 0; j < 4; ++j) {
                    int d = s - j;
                    if (d >= 0 && d <= 20) VA[j] = fma4(P.wu.w[d], v, VA[j]);
                }
            }
            int pb = (vc & 1) * 208, ci = vc >> 1;
            #pragma unroll
            for (int j = 0; j < 4; ++j) iaE[pb + (vr4 + j) * 26 + ci] = VA[j];
        }
        __syncthreads();                           // Ac + sQ(A) reads + ia writes done
        for (int i = t; i < RIN * CIN; i += 256) {
            int r = i / CIN, c = i - r * CIN;
            int gx = x0 + c - RAD, gy = y0 + r - RAD;
            float4 v = f4(0.f, 0.f, 0.f, 0.f);
            if ((unsigned)gx < W && (unsigned)gy < H) v = P.b_arr[gy * W + gx];
            sQ[i] = v;
        }
        __syncthreads();
        float4 Bc0, Bc1;
        if (t < 128) { Bc0 = sQ[cidx0]; Bc1 = sQ[cidx1]; }
        {
            float4 VB[4];
            if (t < 104) {
                #pragma unroll
                for (int j = 0; j < 4; ++j) VB[j] = f4(0,0,0,0);
                #pragma unroll
                for (int s = 0; s < 24; ++s) {
                    float4 v = sQ[(vr4 + s) * CIN + vc];
                    #pragma unroll
                    for (int j = 0; j < 4; ++j) {
                        int d = s - j;
                        if (d >= 0 && d <= 20) VB[j] = fma4(P.wu.w[d], v, VB[j]);
                    }
                }
            }
            __syncthreads();                       // sQ(B)+Bc reads done
            if (t < 104) {
                int pb = (vc & 1) * 208, ci = vc >> 1;
                #pragma unroll
                for (int j = 0; j < 4; ++j) ibE[pb + (vr4 + j) * 26 + ci] = VB[j];
            }
            __syncthreads();
        }
        if (t < 128) {
            float4 VA0 = f4(0,0,0,0), VA1 = VA0, VB0 = VA0, VB1 = VA0;
            #pragma unroll
            for (int k = 0; k <= 10; ++k) {
                float4 ea = iaE[hb + k], oa = iaE[208 + hb + k];
                float4 eb = ibE[hb + k], ob = ibE[208 + hb + k];
                float wue = P.wu.w[2 * k];
                VA0 = fma4(wue, ea, VA0);  VA1 = fma4(wue, oa, VA1);
                VB0 = fma4(wue, eb, VB0);  VB1 = fma4(wue, ob, VB1);
                if (k < 10) {
                    float wuo = P.wu.w[2 * k + 1];
                    VA0 = fma4(wuo, oa, VA0);
                    VB0 = fma4(wuo, ob, VB0);
                }
                if (k > 0) {
                    float wup = P.wu.w[2 * k - 1];
                    VA1 = fma4(wup, ea, VA1);
                    VB1 = fma4(wup, eb, VB1);
                }
            }
            // pixel 0
            {
                float4 a4 = fma4(-P.c0u, Ac0, VA0);
                float4 b4 = fma4(-P.c0u, Bc0, VB0);
                float lx = fmaf(fmaf(a4.x, gv0, b4.x), ibn0, part0.x);
                float ly = fmaf(fmaf(a4.y, gv0, b4.y), ibn0, part0.y);
                float lz = fmaf(fmaf(a4.z, gv0, b4.z), ibn0, part0.z);
                float lw = fmaf(fmaf(a4.w, gv0, b4.w), ibn0, part0.w);
                float m = fmaxf(fmaxf(lx, ly), fmaxf(lz, lw));
                float ex = expf(lx - m), ey = expf(ly - m);
                float ez = expf(lz - m), ew = expf(lw - m);
                float inv = 1.f / (ex + ey + ez + ew);
                float4 qn = f4(ex * inv, ey * inv, ez * inv, ew * inv);
                if (it == 4) P.Qfinal[p0] = qn; else P.Q[p0] = qn;
            }
            // pixel 1
            {
                float4 a4 = fma4(-P.c0u, Ac1, VA1);
                float4 b4 = fma4(-P.c0u, Bc1, VB1);
                float lx = fmaf(fmaf(a4.x, gv1, b4.x), ibn1, part1.x);
                float ly = fmaf(fmaf(a4.y, gv1, b4.y), ibn1, part1.y);
                float lz = fmaf(fmaf(a4.z, gv1, b4.z), ibn1, part1.z);
                float lw = fmaf(fmaf(a4.w, gv1, b4.w), ibn1, part1.w);
                float m = fmaxf(fmaxf(lx, ly), fmaxf(lz, lw));
                float ex = expf(lx - m), ey = expf(ly - m);
                float ez = expf(lz - m), ew = expf(lw - m);
                float inv = 1.f / (ex + ey + ez + ew);
                float4 qn = f4(ex * inv, ey * inv, ez * inv, ew * inv);
                if (it == 4) P.Qfinal[p1] = qn; else P.Q[p1] = qn;
            }
        }
        if (it < 4) publish(flags, L, 4 + 2 * it);
    }
}

// ===================== fallback: proven round-5 multi-dispatch ==============

__global__ __launch_bounds__(256) void fb_init(const float* __restrict__ img,
        const float4* __restrict__ unary, float* __restrict__ gray,
        float4* __restrict__ Q, float* __restrict__ Sg, float* __restrict__ Su,
        W21 wg, W21 wu) {
    int t = threadIdx.x;
    if (blockIdx.x < 2) {
        int x = blockIdx.x * 256 + t;
        float sg = 0.f, su = 0.f;
        #pragma unroll
        for (int d = -RAD; d <= RAD; ++d) {
            int xx = x + d;
            if (xx >= 0 && xx < W) { sg += wg.w[d + RAD]; su += wu.w[d + RAD]; }
        }
        Sg[x] = sg; Su[x] = su;
    }
    int b = swz(blockIdx.x, NPIX / 256);
    int p = b * 256 + t;
    float r = img[3 * p], g = img[3 * p + 1], bch = img[3 * p + 2];
    gray[p] = 0.2989f * r + 0.5870f * g + 0.1140f * bch;
    float4 u = unary[p];
    float mn = fminf(fminf(u.x, u.y), fminf(u.z, u.w));
    float ex = expf(mn - u.x), ey = expf(mn - u.y), ez = expf(mn - u.z), ew = expf(mn - u.w);
    float inv = 1.f / (ex + ey + ez + ew);
    Q[p] = f4(ex * inv, ey * inv, ez * inv, ew * inv);
}

__global__ __launch_bounds__(256, 4) void fb_s1(const float* __restrict__ gray,
        const float* __restrict__ Su, float* __restrict__ mean_I,
        float* __restrict__ inv_var, float2* __restrict__ a1b1,
        W21 wu, float c0u) {
    __shared__ float  sg[RIN][CIN];
    __shared__ float2 ii[TY][CIN];
    int L = swz(blockIdx.x, NBLK);
    int x0 = (L & (GX - 1)) * TX, y0 = (L >> 4) * TY;
    int t = threadIdx.x;
    for (int i = t; i < RIN * CIN; i += 256) {
        int r = i / CIN, c = i - r * CIN;
        int gx = x0 + c - RAD, gy = y0 + r - RAD;
        float g = 0.f;
        if ((unsigned)gx < W && (unsigned)gy < H) g = gray[gy * W + gx];
        sg[r][c] = g;
    }
    __syncthreads();
    if (t < NVT) {
        int c = t % CIN, r0 = (t / CIN) * 2;
        float2 acc0 = make_float2(0.f, 0.f), acc1 = acc0;
        #pragma unroll
        for (int s = 0; s < 22; ++s) {
            float g = sg[r0 + s][c];
            if (s <= 20) { float wgv = wu.w[s] * g; acc0.x += wgv; acc0.y = fmaf(wgv, g, acc0.y); }
            if (s >= 1)  { float wgv = wu.w[s-1] * g; acc1.x += wgv; acc1.y = fmaf(wgv, g, acc1.y); }
        }
        ii[r0][c] = acc0; ii[r0 + 1][c] = acc1;
    }
    __syncthreads();
    int row = t >> 5, col = t & 31;
    float2 A = make_float2(0.f, 0.f);
    #pragma unroll
    for (int d = 0; d < KS; ++d) {
        float2 v = ii[row][col + d];
        A.x = fmaf(wu.w[d], v.x, A.x);
        A.y = fmaf(wu.w[d], v.y, A.y);
    }
    int py = y0 + row, px = x0 + col;
    int p = py * W + px;
    float gc = sg[row + RAD][col + RAD];
    float mI = A.x - c0u * gc;
    float mII = A.y - c0u * gc * gc;
    float iv = 1.f / ((mII - mI * mI) + CRF_EPS);
    float N = Su[px] * Su[py] - c0u;
    float av = mI * (1.f - N) * iv;
    float bv = N - av * mI;
    mean_I[p] = mI; inv_var[p] = iv; a1b1[p] = make_float2(av, bv);
}

__global__ __launch_bounds__(256, 4) void fb_s2(const float2* __restrict__ a1b1,
        const float* __restrict__ gray, float* __restrict__ inv_bn,
        W21 wu, float c0u) {
    __shared__ float2 s2[RIN][CIN];
    __shared__ float2 ii[TY][CIN];
    int L = swz(blockIdx.x, NBLK);
    int x0 = (L & (GX - 1)) * TX, y0 = (L >> 4) * TY;
    int t = threadIdx.x;
    for (int i = t; i < RIN * CIN; i += 256) {
        int r = i / CIN, c = i - r * CIN;
        int gx = x0 + c - RAD, gy = y0 + r - RAD;
        float2 v = make_float2(0.f, 0.f);
        if ((unsigned)gx < W && (unsigned)gy < H) v = a1b1[gy * W + gx];
        s2[r][c] = v;
    }
    __syncthreads();
    if (t < NVT) {
        int c = t % CIN, r0 = (t / CIN) * 2;
        float2 acc0 = make_float2(0.f, 0.f), acc1 = acc0;
        #pragma unroll
        for (int s = 0; s < 22; ++s) {
            float2 v = s2[r0 + s][c];
            if (s <= 20) { acc0.x = fmaf(wu.w[s], v.x, acc0.x); acc0.y = fmaf(wu.w[s], v.y, acc0.y); }
            if (s >= 1)  { acc1.x = fmaf(wu.w[s-1], v.x, acc1.x); acc1.y = fmaf(wu.w[s-1], v.y, acc1.y); }
        }
        ii[r0][c] = acc0; ii[r0 + 1][c] = acc1;
    }
    __syncthreads();
    int row = t >> 5, col = t & 31;
    float2 A = make_float2(0.f, 0.f);
    #pragma unroll
    for (int d = 0; d < KS; ++d) {
        float2 v = ii[row][col + d];
        A.x = fmaf(wu.w[d], v.x, A.x);
        A.y = fmaf(wu.w[d], v.y, A.y);
    }
    int p = (y0 + row) * W + x0 + col;
    float2 cen = s2[row + RAD][col + RAD];
    float va = A.x - c0u * cen.x;
    float vb = A.y - c0u * cen.y;
    inv_bn[p] = 1.f / (va * gray[p] + vb);
}

__global__ __launch_bounds__(256, 4) void fb_f1(const float4* __restrict__ Q,
        const float* __restrict__ gray, const float* __restrict__ mean_I,
        const float* __restrict__ inv_var, const float* __restrict__ Sg,
        const float4* __restrict__ unary, float4* __restrict__ a_out,
        float4* __restrict__ b_out, float4* __restrict__ partial,
        W21 wg, W21 wu, float c0g, float c0u) {
    __shared__ __align__(16) char smem[23296 + 5824 + 6656];
    float4* sQ = (float4*)smem;
    float*  sG = (float*)(smem + 23296);
    float4* i2 = (float4*)(smem + 23296 + 5824);
    float4* i0 = (float4*)smem;
    float4* i1 = (float4*)(smem + 6656);
    int L = swz(blockIdx.x, NBLK);
    int x0 = (L & (GX - 1)) * TX, y0 = (L >> 4) * TY;
    int t = threadIdx.x;
    for (int i = t; i < RIN * CIN; i += 256) {
        int r = i / CIN, c = i - r * CIN;
        int gx = x0 + c - RAD, gy = y0 + r - RAD;
        float4 q = f4(0.f, 0.f, 0.f, 0.f); float g = 0.f;
        if ((unsigned)gx < W && (unsigned)gy < H) {
            int p = gy * W + gx; q = Q[p]; g = gray[p];
        }
        sQ[i] = q; sG[i] = g;
    }
    __syncthreads();
    int row = t >> 5, col = t & 31;
    int py = y0 + row, px = x0 + col;
    int p = py * W + px;
    float mI = mean_I[p], iv = inv_var[p];
    float4 u = unary[p];
    float sgx = Sg[px], sgy = Sg[py];
    float4 Qc = sQ[(row + RAD) * CIN + col + RAD];
    float  gc = sG[(row + RAD) * CIN + col + RAD];
    float4 a0[2], a1[2], a2[2];
    int vc = t % CIN, vr0 = (t / CIN) * 2;
    if (t < NVT) {
        #pragma unroll
        for (int j = 0; j < 2; ++j) { a0[j] = f4(0,0,0,0); a1[j] = a0[j]; a2[j] = a0[j]; }
        #pragma unroll
        for (int s = 0; s < 22; ++s) {
            float4 q = sQ[(vr0 + s) * CIN + vc];
            float g = sG[(vr0 + s) * CIN + vc];
            float4 gq = f4(g * q.x, g * q.y, g * q.z, g * q.w);
            if (s <= 20) {
                a0[0] = fma4(wg.w[s], q, a0[0]);
                a1[0] = fma4(wu.w[s], q, a1[0]);
                a2[0] = fma4(wu.w[s], gq, a2[0]);
            }
            if (s >= 1) {
                a0[1] = fma4(wg.w[s-1], q, a0[1]);
                a1[1] = fma4(wu.w[s-1], q, a1[1]);
                a2[1] = fma4(wu.w[s-1], gq, a2[1]);
            }
        }
    }
    __syncthreads();
    if (t < NVT) {
        #pragma unroll
        for (int j = 0; j < 2; ++j) {
            i0[(vr0 + j) * CIN + vc] = a0[j];
            i1[(vr0 + j) * CIN + vc] = a1[j];
            i2[(vr0 + j) * CIN + vc] = a2[j];
        }
    }
    __syncthreads();
    float4 A0 = f4(0,0,0,0), A1 = A0, A2 = A0;
    #pragma unroll
    for (int d = 0; d < KS; ++d) {
        A0 = fma4(wg.w[d], i0[row * CIN + col + d], A0);
        A1 = fma4(wu.w[d], i1[row * CIN + col + d], A1);
        A2 = fma4(wu.w[d], i2[row * CIN + col + d], A2);
    }
    float4 g4  = fma4(-c0g, Qc, A0);
    float4 m4  = fma4(-c0u, Qc, A1);
    float4 mi4 = fma4(-c0u * gc, Qc, A2);
    float4 a, b;
    a.x = (mi4.x - mI * m4.x) * iv; a.y = (mi4.y - mI * m4.y) * iv;
    a.z = (mi4.z - mI * m4.z) * iv; a.w = (mi4.w - mI * m4.w) * iv;
    b.x = m4.x - a.x * mI; b.y = m4.y - a.y * mI;
    b.z = m4.z - a.z * mI; b.w = m4.w - a.w * mI;
    float s3 = 3.f / (sgx * sgy - c0g);
    float4 part = f4(fmaf(s3, g4.x, -u.x), fmaf(s3, g4.y, -u.y),
                     fmaf(s3, g4.z, -u.z), fmaf(s3, g4.w, -u.w));
    a_out[p] = a; b_out[p] = b; partial[p] = part;
}

__global__ __launch_bounds__(256, 4) void fb_f2(const float4* __restrict__ A,
        const float4* __restrict__ B, const float4* __restrict__ partial,
        const float* __restrict__ gray, const float* __restrict__ inv_bn,
        float4* __restrict__ Qout, W21 wu, float c0u) {
    __shared__ __align__(16) char smem[23296 + 6656];
    float4* sT = (float4*)smem;
    float4* ia = (float4*)(smem + 23296);
    float4* ib = (float4*)smem;
    int L = swz(blockIdx.x, NBLK);
    int x0 = (L & (GX - 1)) * TX, y0 = (L >> 4) * TY;
    int t = threadIdx.x;
    int row = t >> 5, col = t & 31;
    int py = y0 + row, px = x0 + col;
    int p = py * W + px;
    int vc = t % CIN, vr0 = (t / CIN) * 2;
    float gv = gray[p];
    float ibn = 10.f * inv_bn[p];
    float4 part = partial[p];
    for (int i = t; i < RIN * CIN; i += 256) {
        int r = i / CIN, c = i - r * CIN;
        int gx = x0 + c - RAD, gy = y0 + r - RAD;
        float4 v = f4(0.f, 0.f, 0.f, 0.f);
        if ((unsigned)gx < W && (unsigned)gy < H) v = A[gy * W + gx];
        sT[i] = v;
    }
    __syncthreads();
    float4 Ac = sT[(row + RAD) * CIN + col + RAD];
    float4 va0 = f4(0,0,0,0), va1 = va0;
    if (t < NVT) {
        #pragma unroll
        for (int s = 0; s < 22; ++s) {
            float4 v = sT[(vr0 + s) * CIN + vc];
            if (s <= 20) va0 = fma4(wu.w[s], v, va0);
            if (s >= 1)  va1 = fma4(wu.w[s-1], v, va1);
        }
        ia[vr0 * CIN + vc] = va0;
        ia[(vr0 + 1) * CIN + vc] = va1;
    }
    __syncthreads();
    for (int i = t; i < RIN * CIN; i += 256) {
        int r = i / CIN, c = i - r * CIN;
        int gx = x0 + c - RAD, gy = y0 + r - RAD;
        float4 v = f4(0.f, 0.f, 0.f, 0.f);
        if ((unsigned)gx < W && (unsigned)gy < H) v = B[gy * W + gx];
        sT[i] = v;
    }
    __syncthreads();
    float4 Bc = sT[(row + RAD) * CIN + col + RAD];
    float4 vb0 = f4(0,0,0,0), vb1 = vb0;
    if (t < NVT) {
        #pragma unroll
        for (int s = 0; s < 22; ++s) {
            float4 v = sT[(vr0 + s) * CIN + vc];
            if (s <= 20) vb0 = fma4(wu.w[s], v, vb0);
            if (s >= 1)  vb1 = fma4(wu.w[s-1], v, vb1);
        }
    }
    __syncthreads();
    if (t < NVT) {
        ib[vr0 * CIN + vc] = vb0;
        ib[(vr0 + 1) * CIN + vc] = vb1;
    }
    __syncthreads();
    float4 VA = f4(0,0,0,0), VB = VA;
    #pragma unroll
    for (int d = 0; d < KS; ++d) {
        VA = fma4(wu.w[d], ia[row * CIN + col + d], VA);
        VB = fma4(wu.w[d], ib[row * CIN + col + d], VB);
    }
    float4 a4 = fma4(-c0u, Ac, VA);
    float4 b4 = fma4(-c0u, Bc, VB);
    float lx = fmaf(fmaf(a4.x, gv, b4.x), ibn, part.x);
    float ly = fmaf(fmaf(a4.y, gv, b4.y), ibn, part.y);
    float lz = fmaf(fmaf(a4.z, gv, b4.z), ibn, part.z);
    float lw = fmaf(fmaf(a4.w, gv, b4.w), ibn, part.w);
    float m = fmaxf(fmaxf(lx, ly), fmaxf(lz, lw));
    float ex = expf(lx - m), ey = expf(ly - m), ez = expf(lz - m), ew = expf(lw - m);
    float inv = 1.f / (ex + ey + ez + ew);
    Qout[p] = f4(ex * inv, ey * inv, ez * inv, ew * inv);
}

// ---- host ----

static void make_w_host(double theta, W21* w, float* c0) {
    double tmp[KS], s = 0.0;
    for (int d = -RAD; d <= RAD; ++d) {
        double v = exp(-(double)(d * d) / (2.0 * theta * theta));
        tmp[d + RAD] = v; s += v;
    }
    for (int i = 0; i < KS; ++i) w->w[i] = (float)(tmp[i] / s);
    *c0 = (float)(1.0 / (s * s));   // normalized 2D center weight
}

extern "C" void kernel_launch(void* const* d_in, const int* in_sizes, int n_in,
                              void* d_out, int out_size, void* d_ws, size_t ws_size,
                              hipStream_t stream) {
    const float4* unary = (const float4*)d_in[0];
    const float* image = (const float*)d_in[1];
    float* wsf = (float*)d_ws;

    float*  gray    = wsf;
    float*  mean_I  = wsf + 262144;   // coop path reuses this region for flags
    float*  inv_var = wsf + 524288;
    float2* a1b1    = (float2*)(wsf + 786432);
    float*  inv_bn  = wsf + 1310720;
    float*  Sg      = wsf + 1572864;
    float*  Su      = wsf + 1573376;
    float4* Q       = (float4*)(wsf + 1573888);
    float4* partial = (float4*)(wsf + 2622464);
    float4* a_arr   = (float4*)(wsf + 3671040);
    float4* b_arr   = (float4*)(wsf + 4719616);
    unsigned* flags = (unsigned*)(wsf + 262144);   // 1024 * 128 B = 128 KiB

    W21 wg, wu; float c0g, c0u;
    make_w_host(2.5, &wg, &c0g);
    make_w_host(10.0 / 3.0, &wu, &c0u);

    // deterministic cooperative-capacity pre-check (host-only, capture-safe)
    int dev = 0;
    (void)hipGetDevice(&dev);
    int coop = 0, nCU = 0, blkPerCU = 0;
    (void)hipDeviceGetAttribute(&coop, hipDeviceAttributeCooperativeLaunch, dev);
    (void)hipDeviceGetAttribute(&nCU, hipDeviceAttributeMultiprocessorCount, dev);
    (void)hipOccupancyMaxActiveBlocksPerMultiprocessor(&blkPerCU,
            (const void*)k_crf, 256, 0);
    bool useCoop = (coop != 0) && ((long)blkPerCU * nCU >= NBLK);

    hipError_t st = hipErrorUnknown;
    if (useCoop) {
        // reset neighbor-sync flags (stream-ordered, graph-capture-safe)
        (void)hipMemsetAsync(flags, 0, (size_t)NBLK * FLAG_STRIDE * sizeof(unsigned),
                             stream);
        Params P;
        P.unary = unary; P.image = image; P.gray = gray; P.Q = Q;
        P.a1b1 = a1b1; P.a_arr = a_arr; P.b_arr = b_arr;
        P.Qfinal = (float4*)d_out; P.flags = flags;
        P.wg = wg; P.wu = wu; P.c0g = c0g; P.c0u = c0u;
        void* args[] = { &P };
        st = hipLaunchCooperativeKernel((const void*)k_crf, dim3(NBLK), dim3(256),
                                        args, 0, stream);
    }
    if (st != hipSuccess) {
        dim3 bl(256), grEl(NPIX / 256), grT(NBLK);
        fb_init<<<grEl, bl, 0, stream>>>(image, unary, gray, Q, Sg, Su, wg, wu);
        fb_s1<<<grT, bl, 0, stream>>>(gray, Su, mean_I, inv_var, a1b1, wu, c0u);
        fb_s2<<<grT, bl, 0, stream>>>(a1b1, gray, inv_bn, wu, c0u);
        for (int it = 0; it < 5; ++it) {
            fb_f1<<<grT, bl, 0, stream>>>(Q, gray, mean_I, inv_var, Sg,
                                          unary, a_arr, b_arr, partial, wg, wu, c0g, c0u);
            float4* qdst = (it == 4) ? (float4*)d_out : Q;
            fb_f2<<<grT, bl, 0, stream>>>(a_arr, b_arr, partial, gray, inv_bn, qdst,
                                          wu, c0u);
        }
    }
}